// Round 6
// baseline (1049.078 us; speedup 1.0000x reference)
//
#include <hip/hip_runtime.h>
#include <math.h>

constexpr int CN = 4096, CHH = 8, CD = 64, CM = 128;
constexpr int V1P_OFF = 16 * 4096 * 8 * 64;             // 33554432 floats
constexpr int V2P_OFF = V1P_OFF + 16 * 4096 * 8 * 128;  // 100663296 floats
constexpr float KSCALE = 0.35355339059327373f;          // 64^-0.25 (tau=1)
constexpr float KRATIO = 0.08838834764831843f;          // 1/sqrt(128)
constexpr float KEPS   = 1e-6f;

__device__ __forceinline__ float dot4(float4 a, float4 b) {
  return fmaf(a.x, b.x, fmaf(a.y, b.y, fmaf(a.z, b.z, a.w * b.w)));
}
__device__ __forceinline__ float4 scl4(float4 a, float s) {
  return make_float4(a.x * s, a.y * s, a.z * s, a.w * s);
}
__device__ __forceinline__ void fma4(float4& a, float s, float4 b) {
  a.x = fmaf(s, b.x, a.x); a.y = fmaf(s, b.y, a.y);
  a.z = fmaf(s, b.z, a.z); a.w = fmaf(s, b.w, a.w);
}
__device__ __forceinline__ float expv(float s, float c) {
  return KRATIO * (__expf(s + c) + KEPS);
}

// ---- K2e: e = exp(dd - diag) (unshifted) + per-block raw-dd max.
//      R=2 rows/thread. Needs ~170 VGPR -> launch_bounds(256,1) to stop
//      the occupancy heuristic from spilling (r5: k4a got 88 VGPR + spills).
__global__ __launch_bounds__(256, 1) void k2e(
    const float* __restrict__ nv2, const float* __restrict__ proj,
    float* __restrict__ e_out, float* __restrict__ partmax) {
  __shared__ float4 pj[2048];   // proj [128 j][16 f4] 32KB
  __shared__ float red[256];
  for (int i = threadIdx.x; i < 2048; i += 256) pj[i] = ((const float4*)proj)[i];
  __syncthreads();
  const int bh = blockIdx.x >> 3, ch = blockIdx.x & 7;
  const int b = bh >> 3, h = bh & 7;
  const int n0 = ch * 512 + threadIdx.x;          // rows n0, n0+256
  const size_t r0 = (size_t)((b * CN + n0) * CHH + h);
  const size_t r1 = (size_t)((b * CN + n0 + 256) * CHH + h);
  const float4* a0 = (const float4*)(nv2 + r0 * CD);
  const float4* a1 = (const float4*)(nv2 + r1 * CD);
  float4 v0[16], v1[16];
#pragma unroll
  for (int q = 0; q < 16; q++) { v0[q] = scl4(a0[q], KSCALE); v1[q] = scl4(a1[q], KSCALE); }
  float d0 = 0.f, d1 = 0.f;
#pragma unroll
  for (int q = 0; q < 16; q++) { d0 += dot4(v0[q], v0[q]); d1 += dot4(v1[q], v1[q]); }
  const float c0 = -0.5f * d0, c1 = -0.5f * d1;   // NO max shift here
  float4* o0 = (float4*)(e_out + r0 * CM);
  float4* o1 = (float4*)(e_out + r1 * CM);
  float mx = -1e30f;
  for (int jb = 0; jb < 16; jb++) {               // 16 chunks x 8 j
    float s0[8], s1[8];
#pragma unroll
    for (int jj = 0; jj < 8; jj++) {
      const float4* p = &pj[(jb * 8 + jj) * 16];
      float a0s = 0.f, a1s = 0.f, b0s = 0.f, b1s = 0.f;
#pragma unroll
      for (int q = 0; q < 16; q += 2) {
        float4 pa = p[q], pb = p[q + 1];
        a0s += dot4(v0[q], pa); a1s += dot4(v0[q + 1], pb);
        b0s += dot4(v1[q], pa); b1s += dot4(v1[q + 1], pb);
      }
      s0[jj] = a0s + a1s; s1[jj] = b0s + b1s;
      mx = fmaxf(mx, fmaxf(s0[jj], s1[jj]));
    }
#pragma unroll
    for (int u = 0; u < 2; u++) {
      o0[jb * 2 + u] = make_float4(__expf(s0[u * 4 + 0] + c0), __expf(s0[u * 4 + 1] + c0),
                                   __expf(s0[u * 4 + 2] + c0), __expf(s0[u * 4 + 3] + c0));
      o1[jb * 2 + u] = make_float4(__expf(s1[u * 4 + 0] + c1), __expf(s1[u * 4 + 1] + c1),
                                   __expf(s1[u * 4 + 2] + c1), __expf(s1[u * 4 + 3] + c1));
    }
  }
  red[threadIdx.x] = mx;
  __syncthreads();
  for (int s = 128; s > 0; s >>= 1) {
    if ((int)threadIdx.x < s) red[threadIdx.x] = fmaxf(red[threadIdx.x], red[threadIdx.x + s]);
    __syncthreads();
  }
  if (threadIdx.x == 0) partmax[blockIdx.x] = red[0];
}

// ---- K2b: per-bh scale factor s = exp(-max)
__global__ void k2b_scale(const float* __restrict__ partmax, float* __restrict__ sfac) {
  const int bh = threadIdx.x;  // 128 threads
  float m = -1e30f;
#pragma unroll
  for (int c = 0; c < 8; c++) m = fmaxf(m, partmax[bh * 8 + c]);
  sfac[bh] = __expf(-m);
}

// ---- K3v: v2p = ratio*(e*s + eps) (written out) + partial v2x GEMM.
//      Reg-prefetch double-buffered LDS tiles.
__global__ __launch_bounds__(256) void k3v(
    const float* __restrict__ e_in, const float* __restrict__ x,
    const float* __restrict__ sfac, float* __restrict__ v2p_out,
    float* __restrict__ part, float* __restrict__ vsumpart) {
  __shared__ float4 tv[1024];  // v2p tile [32 n][32 f4 = 128 j] 16KB
  __shared__ float4 tx[512];   // x   tile [32 n][16 f4 =  64 d]  8KB
  const int bh = blockIdx.x >> 3, ch = blockIdx.x & 7;
  const int b = bh >> 3, h = bh & 7;
  const float ss = KRATIO * sfac[bh];
  const float rk = KRATIO * KEPS;
  const int tj = threadIdx.x >> 3, td = threadIdx.x & 7;  // tj 0..31, td 0..7
  float acc[4][8];
  float vs[4] = {0.f, 0.f, 0.f, 0.f};
#pragma unroll
  for (int i = 0; i < 4; i++)
#pragma unroll
    for (int k = 0; k < 8; k++) acc[i][k] = 0.f;
  float4 rv[4], rx[2];
  // prefetch tile 0 (scale e -> v2p, write back final v2p, keep in regs)
  {
    const int nb = ch * 512;
#pragma unroll
    for (int k = 0; k < 4; k++) {
      const int q = threadIdx.x + k * 256, nn = q >> 5, c4 = q & 31;
      const size_t r = (size_t)((b * CN + nb + nn) * CHH + h);
      float4 ev = *((const float4*)(e_in + r * CM) + c4);
      float4 sv = make_float4(fmaf(ev.x, ss, rk), fmaf(ev.y, ss, rk),
                              fmaf(ev.z, ss, rk), fmaf(ev.w, ss, rk));
      *((float4*)(v2p_out + r * CM) + c4) = sv;
      rv[k] = sv;
    }
#pragma unroll
    for (int k = 0; k < 2; k++) {
      const int q = threadIdx.x + k * 256, nn = q >> 4, c4 = q & 15;
      rx[k] = *((const float4*)(x + (size_t)((b * CN + nb + nn) * CHH + h) * CD) + c4);
    }
  }
  for (int t = 0; t < 16; t++) {
    __syncthreads();
#pragma unroll
    for (int k = 0; k < 4; k++) tv[threadIdx.x + k * 256] = rv[k];
#pragma unroll
    for (int k = 0; k < 2; k++) tx[threadIdx.x + k * 256] = rx[k];
    __syncthreads();
    if (t < 15) {  // issue next-tile loads; latency hides under compute below
      const int nb = ch * 512 + (t + 1) * 32;
#pragma unroll
      for (int k = 0; k < 4; k++) {
        const int q = threadIdx.x + k * 256, nn = q >> 5, c4 = q & 31;
        const size_t r = (size_t)((b * CN + nb + nn) * CHH + h);
        float4 ev = *((const float4*)(e_in + r * CM) + c4);
        float4 sv = make_float4(fmaf(ev.x, ss, rk), fmaf(ev.y, ss, rk),
                                fmaf(ev.z, ss, rk), fmaf(ev.w, ss, rk));
        *((float4*)(v2p_out + r * CM) + c4) = sv;
        rv[k] = sv;
      }
#pragma unroll
      for (int k = 0; k < 2; k++) {
        const int q = threadIdx.x + k * 256, nn = q >> 4, c4 = q & 15;
        rx[k] = *((const float4*)(x + (size_t)((b * CN + nb + nn) * CHH + h) * CD) + c4);
      }
    }
    for (int nn = 0; nn < 32; nn++) {
      float4 aa = tv[nn * 32 + tj];
      float4 x0 = tx[nn * 16 + td * 2], x1 = tx[nn * 16 + td * 2 + 1];
      float av[4] = {aa.x, aa.y, aa.z, aa.w};
#pragma unroll
      for (int jj = 0; jj < 4; jj++) {
        acc[jj][0] = fmaf(av[jj], x0.x, acc[jj][0]);
        acc[jj][1] = fmaf(av[jj], x0.y, acc[jj][1]);
        acc[jj][2] = fmaf(av[jj], x0.z, acc[jj][2]);
        acc[jj][3] = fmaf(av[jj], x0.w, acc[jj][3]);
        acc[jj][4] = fmaf(av[jj], x1.x, acc[jj][4]);
        acc[jj][5] = fmaf(av[jj], x1.y, acc[jj][5]);
        acc[jj][6] = fmaf(av[jj], x1.z, acc[jj][6]);
        acc[jj][7] = fmaf(av[jj], x1.w, acc[jj][7]);
      }
      vs[0] += aa.x; vs[1] += aa.y; vs[2] += aa.z; vs[3] += aa.w;
    }
  }
  const size_t pbase = (size_t)blockIdx.x * 8192;
#pragma unroll
  for (int jj = 0; jj < 4; jj++) {
    *(float4*)(part + pbase + (tj * 4 + jj) * 64 + td * 8) =
        make_float4(acc[jj][0], acc[jj][1], acc[jj][2], acc[jj][3]);
    *(float4*)(part + pbase + (tj * 4 + jj) * 64 + td * 8 + 4) =
        make_float4(acc[jj][4], acc[jj][5], acc[jj][6], acc[jj][7]);
  }
  if (td == 0) {
#pragma unroll
    for (int jj = 0; jj < 4; jj++) vsumpart[blockIdx.x * 128 + tj * 4 + jj] = vs[jj];
  }
}

// ---- K3b: reduce 8 partials -> v2x, v2sum  (grid EXACTLY 4160, guarded)
__global__ void k3b_reduce(const float* __restrict__ part, const float* __restrict__ vsumpart,
                           float* __restrict__ v2x, float* __restrict__ vsum) {
  const int i = blockIdx.x * 256 + threadIdx.x;   // covers 1048576 + 16384
  if (i < 1048576) {
    const int bh = i >> 13, r = i & 8191;
    float s = 0.f;
#pragma unroll
    for (int c = 0; c < 8; c++) s += part[(size_t)(bh * 8 + c) * 8192 + r];
    v2x[i] = s;
  } else if (i < 1048576 + 16384) {
    const int k = i - 1048576, bh = k >> 7, j = k & 127;
    float s = 0.f;
#pragma unroll
    for (int c = 0; c < 8; c++) s += vsumpart[(bh * 8 + c) * 128 + j];
    vsum[k] = s;
  }
}

// ---- K4a: v1p. proj in LDS; 2 waves split feature dim; dd[64]+v[64] regs.
//      Needs ~170 VGPR -> launch_bounds(256,1): r5 showed the default
//      heuristic allocated 88 VGPR and spilled dd to scratch (395us).
__global__ __launch_bounds__(256, 1) void k4a_v1p(
    const float* __restrict__ nv1, const float* __restrict__ proj,
    float* __restrict__ v1p) {
  __shared__ float4 pj[2048];
  __shared__ float hm[2][128];
  for (int i = threadIdx.x; i < 2048; i += 256) pj[i] = ((const float4*)proj)[i];
  __syncthreads();
  const int bh = blockIdx.x >> 5, ch = blockIdx.x & 31;
  const int b = bh >> 3, h = bh & 7;
  const int wave = threadIdx.x >> 6, lane = threadIdx.x & 63;
  const int fh = wave & 1;                        // feature half (wave-uniform)
  const int rloc = (wave >> 1) * 64 + lane;       // 0..127
  const int n = ch * 128 + rloc;
  const size_t r = (size_t)((b * CN + n) * CHH + h);
  const float4* a = (const float4*)(nv1 + r * CD);
  float4 v[16];
#pragma unroll
  for (int q = 0; q < 16; q++) v[q] = scl4(a[q], KSCALE);
  float diag = 0.f;
#pragma unroll
  for (int q = 0; q < 16; q++) diag += dot4(v[q], v[q]);
  float dd[64];
#pragma unroll
  for (int j = 0; j < 64; j += 2) {
    const float4* p0 = &pj[(fh * 64 + j) * 16];
    const float4* p1 = p0 + 16;
    float a0 = 0.f, a1 = 0.f, b0 = 0.f, b1 = 0.f;
#pragma unroll
    for (int q = 0; q < 16; q += 2) {
      a0 += dot4(v[q], p0[q]);     a1 += dot4(v[q + 1], p0[q + 1]);
      b0 += dot4(v[q], p1[q]);     b1 += dot4(v[q + 1], p1[q + 1]);
    }
    dd[j] = a0 + a1; dd[j + 1] = b0 + b1;
  }
  float m0 = -1e30f, m1 = -1e30f, m2 = -1e30f, m3 = -1e30f;
#pragma unroll
  for (int j = 0; j < 64; j += 4) {
    m0 = fmaxf(m0, dd[j]); m1 = fmaxf(m1, dd[j + 1]);
    m2 = fmaxf(m2, dd[j + 2]); m3 = fmaxf(m3, dd[j + 3]);
  }
  hm[fh][rloc] = fmaxf(fmaxf(m0, m1), fmaxf(m2, m3));
  __syncthreads();
  const float c = -(0.5f * diag + fmaxf(hm[0][rloc], hm[1][rloc]));
  float4* o = (float4*)(v1p + r * CM + fh * 64);
#pragma unroll
  for (int q = 0; q < 16; q++)
    o[q] = make_float4(expv(dd[q * 4 + 0], c), expv(dd[q * 4 + 1], c),
                       expv(dd[q * 4 + 2], c), expv(dd[q * 4 + 3], c));
}

// ---- K4b: out0 = (v1p @ v2x) / (v1p . v2sum). v2x + vsum + v1p tiles in LDS.
__global__ __launch_bounds__(256) void k4b_out(
    const float* __restrict__ v1p, const float* __restrict__ v2xg,
    const float* __restrict__ vsumg, float* __restrict__ out0) {
  __shared__ float4 xv[2048];      // v2x [128 j][16 f4]  32KB
  __shared__ float vsh[128];
  __shared__ float tp[256 * 18];   // v1p^T tile [256 rows][16 j] pad 18  18KB
  const int bh = blockIdx.x >> 4, ch = blockIdx.x & 15;
  const int b = bh >> 3, h = bh & 7;
  for (int i = threadIdx.x; i < 2048; i += 256) xv[i] = *((const float4*)v2xg + (size_t)bh * 2048 + i);
  if (threadIdx.x < 128) vsh[threadIdx.x] = vsumg[bh * 128 + threadIdx.x];
  const int nloc = threadIdx.x;
  const int nbase = ch * 256;
  float4 acc4[16];
#pragma unroll
  for (int q = 0; q < 16; q++) acc4[q] = make_float4(0.f, 0.f, 0.f, 0.f);
  float o2 = 0.f;
  for (int jb = 0; jb < 8; jb++) {
    __syncthreads();
    for (int i = threadIdx.x; i < 2048; i += 256) {
      const int row = i >> 3, q = i & 7;  // 8 float2 per row = 16 j
      const float2 t = *((const float2*)(v1p + (size_t)((b * CN + nbase + row) * CHH + h) * CM + jb * 16) + q);
      *(float2*)(&tp[row * 18 + q * 2]) = t;
    }
    __syncthreads();
#pragma unroll
    for (int j = 0; j < 16; j++) {
      const int jg = jb * 16 + j;
      const float p = tp[nloc * 18 + j];
      const float4* xr = &xv[jg * 16];
#pragma unroll
      for (int q = 0; q < 16; q++) fma4(acc4[q], p, xr[q]);
      o2 = fmaf(p, vsh[jg], o2);
    }
  }
  const float inv = 1.0f / o2;
  float4* ob = (float4*)(out0 + (size_t)((b * CN + nbase + nloc) * CHH + h) * CD);
#pragma unroll
  for (int q = 0; q < 16; q++) ob[q] = scl4(acc4[q], inv);
}

extern "C" void kernel_launch(void* const* d_in, const int* in_sizes, int n_in,
                              void* d_out, int out_size, void* d_ws, size_t ws_size,
                              hipStream_t stream) {
  (void)in_sizes; (void)n_in; (void)out_size; (void)ws_size;
  const float* x    = (const float*)d_in[0];
  const float* nv1  = (const float*)d_in[1];
  const float* nv2  = (const float*)d_in[2];
  const float* proj = (const float*)d_in[3];
  float* out  = (float*)d_out;
  float* out0 = out;
  float* v1p  = out + V1P_OFF;
  float* v2p  = out + V2P_OFF;

  // Scratch inside the v1p output region (dead before k4a writes v1p):
  float* part     = v1p;                  // 1024*8192 = 8,388,608 floats
  float* partmax  = v1p + 8388608;        // 1,024
  float* vsumpart = v1p + 8389632;        // 1024*128 = 131,072
  // Persistent scratch in ws (~4.3 MB): survives into k4b.
  float* ws   = (float*)d_ws;
  float* sfac = ws;                       // 128
  float* vsum = ws + 128;                 // 16,384
  float* v2x  = ws + 16512;               // 1,048,576

  k2e      <<<dim3(1024), dim3(256), 0, stream>>>(nv2, proj, v2p, partmax);
  k2b_scale<<<dim3(1),    dim3(128), 0, stream>>>(partmax, sfac);
  k3v      <<<dim3(1024), dim3(256), 0, stream>>>(v2p, x, sfac, v2p, part, vsumpart);
  k3b_reduce<<<dim3(4160),dim3(256), 0, stream>>>(part, vsumpart, v2x, vsum);
  k4a_v1p  <<<dim3(4096), dim3(256), 0, stream>>>(nv1, proj, v1p);
  k4b_out  <<<dim3(2048), dim3(256), 0, stream>>>(v1p, v2x, vsum, out0);
}

// Round 7
// 1020.596 us; speedup vs baseline: 1.0279x; 1.0279x over previous
//
#include <hip/hip_runtime.h>
#include <math.h>

constexpr int CN = 4096, CHH = 8, CD = 64, CM = 128;
constexpr int V1P_OFF = 16 * 4096 * 8 * 64;             // 33554432 floats
constexpr int V2P_OFF = V1P_OFF + 16 * 4096 * 8 * 128;  // 100663296 floats
constexpr float KSCALE = 0.35355339059327373f;          // 64^-0.25 (tau=1)
constexpr float KRATIO = 0.08838834764831843f;          // 1/sqrt(128)
constexpr float KEPS   = 1e-6f;

__device__ __forceinline__ float dot4(float4 a, float4 b) {
  return fmaf(a.x, b.x, fmaf(a.y, b.y, fmaf(a.z, b.z, a.w * b.w)));
}
__device__ __forceinline__ float4 scl4(float4 a, float s) {
  return make_float4(a.x * s, a.y * s, a.z * s, a.w * s);
}
__device__ __forceinline__ void fma4(float4& a, float s, float4 b) {
  a.x = fmaf(s, b.x, a.x); a.y = fmaf(s, b.y, a.y);
  a.z = fmaf(s, b.z, a.z); a.w = fmaf(s, b.w, a.w);
}
__device__ __forceinline__ float expv(float s, float c) {
  return KRATIO * (__expf(s + c) + KEPS);
}

// ---- K2e: e = exp(dd - diag) (unshifted) + per-block raw-dd max.
//      R=2 rows/thread (proj reads shared -> 8 FMA per LDS read).
__global__ __launch_bounds__(256) void k2e(
    const float* __restrict__ nv2, const float* __restrict__ proj,
    float* __restrict__ e_out, float* __restrict__ partmax) {
  __shared__ float4 pj[2048];   // proj [128 j][16 f4] 32KB
  __shared__ float red[256];
  for (int i = threadIdx.x; i < 2048; i += 256) pj[i] = ((const float4*)proj)[i];
  __syncthreads();
  const int bh = blockIdx.x >> 3, ch = blockIdx.x & 7;
  const int b = bh >> 3, h = bh & 7;
  const int n0 = ch * 512 + threadIdx.x;          // rows n0, n0+256
  const size_t r0 = (size_t)((b * CN + n0) * CHH + h);
  const size_t r1 = (size_t)((b * CN + n0 + 256) * CHH + h);
  const float4* a0 = (const float4*)(nv2 + r0 * CD);
  const float4* a1 = (const float4*)(nv2 + r1 * CD);
  float4 v0[16], v1[16];
#pragma unroll
  for (int q = 0; q < 16; q++) { v0[q] = scl4(a0[q], KSCALE); v1[q] = scl4(a1[q], KSCALE); }
  float d0 = 0.f, d1 = 0.f;
#pragma unroll
  for (int q = 0; q < 16; q++) { d0 += dot4(v0[q], v0[q]); d1 += dot4(v1[q], v1[q]); }
  const float c0 = -0.5f * d0, c1 = -0.5f * d1;   // NO max shift here
  float4* o0 = (float4*)(e_out + r0 * CM);
  float4* o1 = (float4*)(e_out + r1 * CM);
  float mx = -1e30f;
  for (int jb = 0; jb < 16; jb++) {               // 16 chunks x 8 j
    float s0[8], s1[8];
#pragma unroll
    for (int jj = 0; jj < 8; jj++) {
      const float4* p = &pj[(jb * 8 + jj) * 16];
      float a0s = 0.f, a1s = 0.f, b0s = 0.f, b1s = 0.f;
#pragma unroll
      for (int q = 0; q < 16; q += 2) {
        float4 pa = p[q], pb = p[q + 1];
        a0s += dot4(v0[q], pa); a1s += dot4(v0[q + 1], pb);
        b0s += dot4(v1[q], pa); b1s += dot4(v1[q + 1], pb);
      }
      s0[jj] = a0s + a1s; s1[jj] = b0s + b1s;
      mx = fmaxf(mx, fmaxf(s0[jj], s1[jj]));
    }
#pragma unroll
    for (int u = 0; u < 2; u++) {
      o0[jb * 2 + u] = make_float4(__expf(s0[u * 4 + 0] + c0), __expf(s0[u * 4 + 1] + c0),
                                   __expf(s0[u * 4 + 2] + c0), __expf(s0[u * 4 + 3] + c0));
      o1[jb * 2 + u] = make_float4(__expf(s1[u * 4 + 0] + c1), __expf(s1[u * 4 + 1] + c1),
                                   __expf(s1[u * 4 + 2] + c1), __expf(s1[u * 4 + 3] + c1));
    }
  }
  red[threadIdx.x] = mx;
  __syncthreads();
  for (int s = 128; s > 0; s >>= 1) {
    if ((int)threadIdx.x < s) red[threadIdx.x] = fmaxf(red[threadIdx.x], red[threadIdx.x + s]);
    __syncthreads();
  }
  if (threadIdx.x == 0) partmax[blockIdx.x] = red[0];
}

// ---- K2b: per-bh scale factor s = exp(-max)
__global__ void k2b_scale(const float* __restrict__ partmax, float* __restrict__ sfac) {
  const int bh = threadIdx.x;  // 128 threads
  float m = -1e30f;
#pragma unroll
  for (int c = 0; c < 8; c++) m = fmaxf(m, partmax[bh * 8 + c]);
  sfac[bh] = __expf(-m);
}

// ---- K3v: v2p = ratio*(e*s + eps) (written out) + partial v2x GEMM.
//      Reg-prefetch double-buffered LDS tiles.
__global__ __launch_bounds__(256) void k3v(
    const float* __restrict__ e_in, const float* __restrict__ x,
    const float* __restrict__ sfac, float* __restrict__ v2p_out,
    float* __restrict__ part, float* __restrict__ vsumpart) {
  __shared__ float4 tv[1024];  // v2p tile [32 n][32 f4 = 128 j] 16KB
  __shared__ float4 tx[512];   // x   tile [32 n][16 f4 =  64 d]  8KB
  const int bh = blockIdx.x >> 3, ch = blockIdx.x & 7;
  const int b = bh >> 3, h = bh & 7;
  const float ss = KRATIO * sfac[bh];
  const float rk = KRATIO * KEPS;
  const int tj = threadIdx.x >> 3, td = threadIdx.x & 7;  // tj 0..31, td 0..7
  float acc[4][8];
  float vs[4] = {0.f, 0.f, 0.f, 0.f};
#pragma unroll
  for (int i = 0; i < 4; i++)
#pragma unroll
    for (int k = 0; k < 8; k++) acc[i][k] = 0.f;
  float4 rv[4], rx[2];
  // prefetch tile 0 (scale e -> v2p, write back final v2p, keep in regs)
  {
    const int nb = ch * 512;
#pragma unroll
    for (int k = 0; k < 4; k++) {
      const int q = threadIdx.x + k * 256, nn = q >> 5, c4 = q & 31;
      const size_t r = (size_t)((b * CN + nb + nn) * CHH + h);
      float4 ev = *((const float4*)(e_in + r * CM) + c4);
      float4 sv = make_float4(fmaf(ev.x, ss, rk), fmaf(ev.y, ss, rk),
                              fmaf(ev.z, ss, rk), fmaf(ev.w, ss, rk));
      *((float4*)(v2p_out + r * CM) + c4) = sv;
      rv[k] = sv;
    }
#pragma unroll
    for (int k = 0; k < 2; k++) {
      const int q = threadIdx.x + k * 256, nn = q >> 4, c4 = q & 15;
      rx[k] = *((const float4*)(x + (size_t)((b * CN + nb + nn) * CHH + h) * CD) + c4);
    }
  }
  for (int t = 0; t < 16; t++) {
    __syncthreads();
#pragma unroll
    for (int k = 0; k < 4; k++) tv[threadIdx.x + k * 256] = rv[k];
#pragma unroll
    for (int k = 0; k < 2; k++) tx[threadIdx.x + k * 256] = rx[k];
    __syncthreads();
    if (t < 15) {  // issue next-tile loads; latency hides under compute below
      const int nb = ch * 512 + (t + 1) * 32;
#pragma unroll
      for (int k = 0; k < 4; k++) {
        const int q = threadIdx.x + k * 256, nn = q >> 5, c4 = q & 31;
        const size_t r = (size_t)((b * CN + nb + nn) * CHH + h);
        float4 ev = *((const float4*)(e_in + r * CM) + c4);
        float4 sv = make_float4(fmaf(ev.x, ss, rk), fmaf(ev.y, ss, rk),
                                fmaf(ev.z, ss, rk), fmaf(ev.w, ss, rk));
        *((float4*)(v2p_out + r * CM) + c4) = sv;
        rv[k] = sv;
      }
#pragma unroll
      for (int k = 0; k < 2; k++) {
        const int q = threadIdx.x + k * 256, nn = q >> 4, c4 = q & 15;
        rx[k] = *((const float4*)(x + (size_t)((b * CN + nb + nn) * CHH + h) * CD) + c4);
      }
    }
    for (int nn = 0; nn < 32; nn++) {
      float4 aa = tv[nn * 32 + tj];
      float4 x0 = tx[nn * 16 + td * 2], x1 = tx[nn * 16 + td * 2 + 1];
      float av[4] = {aa.x, aa.y, aa.z, aa.w};
#pragma unroll
      for (int jj = 0; jj < 4; jj++) {
        acc[jj][0] = fmaf(av[jj], x0.x, acc[jj][0]);
        acc[jj][1] = fmaf(av[jj], x0.y, acc[jj][1]);
        acc[jj][2] = fmaf(av[jj], x0.z, acc[jj][2]);
        acc[jj][3] = fmaf(av[jj], x0.w, acc[jj][3]);
        acc[jj][4] = fmaf(av[jj], x1.x, acc[jj][4]);
        acc[jj][5] = fmaf(av[jj], x1.y, acc[jj][5]);
        acc[jj][6] = fmaf(av[jj], x1.z, acc[jj][6]);
        acc[jj][7] = fmaf(av[jj], x1.w, acc[jj][7]);
      }
      vs[0] += aa.x; vs[1] += aa.y; vs[2] += aa.z; vs[3] += aa.w;
    }
  }
  const size_t pbase = (size_t)blockIdx.x * 8192;
#pragma unroll
  for (int jj = 0; jj < 4; jj++) {
    *(float4*)(part + pbase + (tj * 4 + jj) * 64 + td * 8) =
        make_float4(acc[jj][0], acc[jj][1], acc[jj][2], acc[jj][3]);
    *(float4*)(part + pbase + (tj * 4 + jj) * 64 + td * 8 + 4) =
        make_float4(acc[jj][4], acc[jj][5], acc[jj][6], acc[jj][7]);
  }
  if (td == 0) {
#pragma unroll
    for (int jj = 0; jj < 4; jj++) vsumpart[blockIdx.x * 128 + tj * 4 + jj] = vs[jj];
  }
}

// ---- K3b: reduce 8 partials -> v2x, v2sum  (grid EXACTLY 4160, guarded)
__global__ void k3b_reduce(const float* __restrict__ part, const float* __restrict__ vsumpart,
                           float* __restrict__ v2x, float* __restrict__ vsum) {
  const int i = blockIdx.x * 256 + threadIdx.x;   // covers 1048576 + 16384
  if (i < 1048576) {
    const int bh = i >> 13, r = i & 8191;
    float s = 0.f;
#pragma unroll
    for (int c = 0; c < 8; c++) s += part[(size_t)(bh * 8 + c) * 8192 + r];
    v2x[i] = s;
  } else if (i < 1048576 + 16384) {
    const int k = i - 1048576, bh = k >> 7, j = k & 127;
    float s = 0.f;
#pragma unroll
    for (int c = 0; c < 8; c++) s += vsumpart[(bh * 8 + c) * 128 + j];
    vsum[k] = s;
  }
}

// ---- K4amax: per-ROW raw-dd max for v1p. R=2 rows/thread, scalar maxes
//      only (no persistent arrays -> no scratch; r6 lesson: dd[64] never
//      got SROA'd, big-unroll alloca stayed in scratch at 88 VGPR).
__global__ __launch_bounds__(256) void k4amax(
    const float* __restrict__ nv1, const float* __restrict__ proj,
    float* __restrict__ rowmax) {
  __shared__ float4 pj[2048];   // proj [128 j][16 f4] 32KB
  for (int i = threadIdx.x; i < 2048; i += 256) pj[i] = ((const float4*)proj)[i];
  __syncthreads();
  const int bh = blockIdx.x >> 3, ch = blockIdx.x & 7;
  const int b = bh >> 3, h = bh & 7;
  const int n0 = ch * 512 + threadIdx.x;          // rows n0, n0+256
  const size_t r0 = (size_t)((b * CN + n0) * CHH + h);
  const size_t r1 = (size_t)((b * CN + n0 + 256) * CHH + h);
  const float4* a0 = (const float4*)(nv1 + r0 * CD);
  const float4* a1 = (const float4*)(nv1 + r1 * CD);
  float4 v0[16], v1[16];
#pragma unroll
  for (int q = 0; q < 16; q++) { v0[q] = scl4(a0[q], KSCALE); v1[q] = scl4(a1[q], KSCALE); }
  float mx0 = -1e30f, mx1 = -1e30f;
  for (int jb = 0; jb < 16; jb++) {
#pragma unroll
    for (int jj = 0; jj < 8; jj++) {
      const float4* p = &pj[(jb * 8 + jj) * 16];
      float a0s = 0.f, a1s = 0.f, b0s = 0.f, b1s = 0.f;
#pragma unroll
      for (int q = 0; q < 16; q += 2) {
        float4 pa = p[q], pb = p[q + 1];
        a0s += dot4(v0[q], pa); a1s += dot4(v0[q + 1], pb);
        b0s += dot4(v1[q], pa); b1s += dot4(v1[q + 1], pb);
      }
      mx0 = fmaxf(mx0, a0s + a1s);
      mx1 = fmaxf(mx1, b0s + b1s);
    }
  }
  rowmax[r0] = mx0;
  rowmax[r1] = mx1;
}

// ---- K4aexp: v1p = ratio*(exp(dd - diag - rowmax[r]) + eps). k2e shape:
//      transient chunk arrays only.
__global__ __launch_bounds__(256) void k4aexp(
    const float* __restrict__ nv1, const float* __restrict__ proj,
    const float* __restrict__ rowmax, float* __restrict__ v1p) {
  __shared__ float4 pj[2048];
  for (int i = threadIdx.x; i < 2048; i += 256) pj[i] = ((const float4*)proj)[i];
  __syncthreads();
  const int bh = blockIdx.x >> 3, ch = blockIdx.x & 7;
  const int b = bh >> 3, h = bh & 7;
  const int n0 = ch * 512 + threadIdx.x;          // rows n0, n0+256
  const size_t r0 = (size_t)((b * CN + n0) * CHH + h);
  const size_t r1 = (size_t)((b * CN + n0 + 256) * CHH + h);
  const float4* a0 = (const float4*)(nv1 + r0 * CD);
  const float4* a1 = (const float4*)(nv1 + r1 * CD);
  float4 v0[16], v1[16];
#pragma unroll
  for (int q = 0; q < 16; q++) { v0[q] = scl4(a0[q], KSCALE); v1[q] = scl4(a1[q], KSCALE); }
  float d0 = 0.f, d1 = 0.f;
#pragma unroll
  for (int q = 0; q < 16; q++) { d0 += dot4(v0[q], v0[q]); d1 += dot4(v1[q], v1[q]); }
  const float c0 = -(0.5f * d0 + rowmax[r0]);
  const float c1 = -(0.5f * d1 + rowmax[r1]);
  float4* o0 = (float4*)(v1p + r0 * CM);
  float4* o1 = (float4*)(v1p + r1 * CM);
  for (int jb = 0; jb < 16; jb++) {               // 16 chunks x 8 j
    float s0[8], s1[8];
#pragma unroll
    for (int jj = 0; jj < 8; jj++) {
      const float4* p = &pj[(jb * 8 + jj) * 16];
      float a0s = 0.f, a1s = 0.f, b0s = 0.f, b1s = 0.f;
#pragma unroll
      for (int q = 0; q < 16; q += 2) {
        float4 pa = p[q], pb = p[q + 1];
        a0s += dot4(v0[q], pa); a1s += dot4(v0[q + 1], pb);
        b0s += dot4(v1[q], pa); b1s += dot4(v1[q + 1], pb);
      }
      s0[jj] = a0s + a1s; s1[jj] = b0s + b1s;
    }
#pragma unroll
    for (int u = 0; u < 2; u++) {
      o0[jb * 2 + u] = make_float4(expv(s0[u * 4 + 0], c0), expv(s0[u * 4 + 1], c0),
                                   expv(s0[u * 4 + 2], c0), expv(s0[u * 4 + 3], c0));
      o1[jb * 2 + u] = make_float4(expv(s1[u * 4 + 0], c1), expv(s1[u * 4 + 1], c1),
                                   expv(s1[u * 4 + 2], c1), expv(s1[u * 4 + 3], c1));
    }
  }
}

// ---- K4b: out0 = (v1p @ v2x) / (v1p . v2sum). v2x + vsum + v1p tiles in LDS.
__global__ __launch_bounds__(256) void k4b_out(
    const float* __restrict__ v1p, const float* __restrict__ v2xg,
    const float* __restrict__ vsumg, float* __restrict__ out0) {
  __shared__ float4 xv[2048];      // v2x [128 j][16 f4]  32KB
  __shared__ float vsh[128];
  __shared__ float tp[256 * 18];   // v1p^T tile [256 rows][16 j] pad 18  18KB
  const int bh = blockIdx.x >> 4, ch = blockIdx.x & 15;
  const int b = bh >> 3, h = bh & 7;
  for (int i = threadIdx.x; i < 2048; i += 256) xv[i] = *((const float4*)v2xg + (size_t)bh * 2048 + i);
  if (threadIdx.x < 128) vsh[threadIdx.x] = vsumg[bh * 128 + threadIdx.x];
  const int nloc = threadIdx.x;
  const int nbase = ch * 256;
  float4 acc4[16];
#pragma unroll
  for (int q = 0; q < 16; q++) acc4[q] = make_float4(0.f, 0.f, 0.f, 0.f);
  float o2 = 0.f;
  for (int jb = 0; jb < 8; jb++) {
    __syncthreads();
    for (int i = threadIdx.x; i < 2048; i += 256) {
      const int row = i >> 3, q = i & 7;  // 8 float2 per row = 16 j
      const float2 t = *((const float2*)(v1p + (size_t)((b * CN + nbase + row) * CHH + h) * CM + jb * 16) + q);
      *(float2*)(&tp[row * 18 + q * 2]) = t;
    }
    __syncthreads();
#pragma unroll
    for (int j = 0; j < 16; j++) {
      const int jg = jb * 16 + j;
      const float p = tp[nloc * 18 + j];
      const float4* xr = &xv[jg * 16];
#pragma unroll
      for (int q = 0; q < 16; q++) fma4(acc4[q], p, xr[q]);
      o2 = fmaf(p, vsh[jg], o2);
    }
  }
  const float inv = 1.0f / o2;
  float4* ob = (float4*)(out0 + (size_t)((b * CN + nbase + nloc) * CHH + h) * CD);
#pragma unroll
  for (int q = 0; q < 16; q++) ob[q] = scl4(acc4[q], inv);
}

extern "C" void kernel_launch(void* const* d_in, const int* in_sizes, int n_in,
                              void* d_out, int out_size, void* d_ws, size_t ws_size,
                              hipStream_t stream) {
  (void)in_sizes; (void)n_in; (void)out_size; (void)ws_size;
  const float* x    = (const float*)d_in[0];
  const float* nv1  = (const float*)d_in[1];
  const float* nv2  = (const float*)d_in[2];
  const float* proj = (const float*)d_in[3];
  float* out  = (float*)d_out;
  float* out0 = out;
  float* v1p  = out + V1P_OFF;
  float* v2p  = out + V2P_OFF;

  // Scratch inside the v1p output region (dead before k4aexp writes v1p):
  float* part     = v1p;                  // 1024*8192 = 8,388,608 floats
  float* partmax  = v1p + 8388608;        // 1,024
  float* vsumpart = v1p + 8389632;        // 1024*128 = 131,072
  // rowmax scratch in the out0 region (dead until k4b overwrites out0):
  float* rowmax   = out0;                 // 524,288 floats (2 MB)
  // Persistent scratch in ws (~4.3 MB): survives into k4b.
  float* ws   = (float*)d_ws;
  float* sfac = ws;                       // 128
  float* vsum = ws + 128;                 // 16,384
  float* v2x  = ws + 16512;               // 1,048,576

  k2e      <<<dim3(1024), dim3(256), 0, stream>>>(nv2, proj, v2p, partmax);
  k2b_scale<<<dim3(1),    dim3(128), 0, stream>>>(partmax, sfac);
  k3v      <<<dim3(1024), dim3(256), 0, stream>>>(v2p, x, sfac, v2p, part, vsumpart);
  k3b_reduce<<<dim3(4160),dim3(256), 0, stream>>>(part, vsumpart, v2x, vsum);
  k4amax   <<<dim3(1024), dim3(256), 0, stream>>>(nv1, proj, rowmax);
  k4aexp   <<<dim3(1024), dim3(256), 0, stream>>>(nv1, proj, rowmax, v1p);
  k4b_out  <<<dim3(2048), dim3(256), 0, stream>>>(v1p, v2x, vsum, out0);
}

// Round 8
// 679.817 us; speedup vs baseline: 1.5432x; 1.5013x over previous
//
#include <hip/hip_runtime.h>
#include <math.h>

constexpr int CN = 4096, CHH = 8, CD = 64, CM = 128;
constexpr int V1P_OFF = 16 * 4096 * 8 * 64;             // 33554432 floats
constexpr int V2P_OFF = V1P_OFF + 16 * 4096 * 8 * 128;  // 100663296 floats
constexpr float KSCALE = 0.35355339059327373f;          // 64^-0.25 (tau=1)
constexpr float KRATIO = 0.08838834764831843f;          // 1/sqrt(128)
constexpr float KEPS   = 1e-6f;

typedef __attribute__((ext_vector_type(8))) short bf16x8;
typedef __attribute__((ext_vector_type(4))) float f32x4;

__device__ __forceinline__ float dot4(float4 a, float4 b) {
  return fmaf(a.x, b.x, fmaf(a.y, b.y, fmaf(a.z, b.z, a.w * b.w)));
}
__device__ __forceinline__ float4 scl4(float4 a, float s) {
  return make_float4(a.x * s, a.y * s, a.z * s, a.w * s);
}
__device__ __forceinline__ void fma4(float4& a, float s, float4 b) {
  a.x = fmaf(s, b.x, a.x); a.y = fmaf(s, b.y, a.y);
  a.z = fmaf(s, b.z, a.z); a.w = fmaf(s, b.w, a.w);
}
__device__ __forceinline__ short bhi(float f) {
  return (short)(__float_as_uint(f) >> 16);          // truncate to bf16
}
__device__ __forceinline__ float bf2f(short s) {
  return __uint_as_float(((unsigned)(unsigned short)s) << 16);
}
// split 8 floats (two float4) into bf16 hi + lo fragments
__device__ __forceinline__ void split8(float4 u, float4 v, bf16x8& hi, bf16x8& lo) {
  float a[8] = {u.x, u.y, u.z, u.w, v.x, v.y, v.z, v.w};
#pragma unroll
  for (int e = 0; e < 8; e++) {
    short h = bhi(a[e]);
    hi[e] = h;
    lo[e] = bhi(a[e] - bf2f(h));
  }
}

#define MFMA_B16(A, B, C) __builtin_amdgcn_mfma_f32_16x16x32_bf16(A, B, C, 0, 0, 0)

// load proj into B fragments (8 col-tiles x 2 K-halves x hi/lo), ~128 VGPR
#define LOAD_BFRAGS(proj, lm, ko)                                   \
  bf16x8 Bh0[8], Bl0[8], Bh1[8], Bl1[8];                            \
  _Pragma("unroll")                                                 \
  for (int t = 0; t < 8; t++) {                                     \
    const float* pb = (proj) + (t * 16 + (lm)) * 64 + (ko);         \
    float4 p0 = *(const float4*)(pb);                               \
    float4 p1 = *(const float4*)(pb + 4);                           \
    float4 p2 = *(const float4*)(pb + 32);                          \
    float4 p3 = *(const float4*)(pb + 36);                          \
    split8(p0, p1, Bh0[t], Bl0[t]);                                 \
    split8(p2, p3, Bh1[t], Bl1[t]);                                 \
  }

// ---- kp_stat: projection max. ROWMAX=0: per-block (bh-chunk) max of dd.
//      ROWMAX=1: per-row max of dd written to rowmax[].
//      MFMA: proj in regs, zero LDS in inner loop (r7 lesson: LDS pipe
//      shared per-CU was the 3x bottleneck of the VALU projection).
template <int ROWMAX>
__global__ __launch_bounds__(256) void kp_stat(
    const float* __restrict__ inp, const float* __restrict__ proj,
    float* __restrict__ outmax) {
  const int l = threadIdx.x & 63, w = threadIdx.x >> 6;
  const int lm = l & 15, lk = l >> 4, ko = lk * 8;
  LOAD_BFRAGS(proj, lm, ko);
  const int bh = blockIdx.x >> 3, ch = blockIdx.x & 7;
  const int b = bh >> 3, h = bh & 7;
  float bmax = -1e30f;
  for (int s = 0; s < 8; s++) {
    const int nb = ch * 512 + w * 128 + s * 16;
    const size_t rA = (size_t)((b * CN + nb + lm) * CHH + h);
    const float* pa = inp + rA * 64 + ko;
    float4 a0 = scl4(*(const float4*)(pa), KSCALE);
    float4 a1 = scl4(*(const float4*)(pa + 4), KSCALE);
    float4 a2 = scl4(*(const float4*)(pa + 32), KSCALE);
    float4 a3 = scl4(*(const float4*)(pa + 36), KSCALE);
    bf16x8 Ah0, Al0, Ah1, Al1;
    split8(a0, a1, Ah0, Al0);
    split8(a2, a3, Ah1, Al1);
    float rm[4] = {-1e30f, -1e30f, -1e30f, -1e30f};
#pragma unroll
    for (int t = 0; t < 8; t++) {
      f32x4 acc = {0.f, 0.f, 0.f, 0.f};
      acc = MFMA_B16(Ah0, Bh0[t], acc);
      acc = MFMA_B16(Ah1, Bh1[t], acc);
      acc = MFMA_B16(Al0, Bh0[t], acc);
      acc = MFMA_B16(Al1, Bh1[t], acc);
      acc = MFMA_B16(Ah0, Bl0[t], acc);
      acc = MFMA_B16(Ah1, Bl1[t], acc);
#pragma unroll
      for (int r = 0; r < 4; r++) rm[r] = fmaxf(rm[r], acc[r]);
    }
    if (ROWMAX) {
#pragma unroll
      for (int r = 0; r < 4; r++) {
        float v = rm[r];
        v = fmaxf(v, __shfl_xor(v, 1));
        v = fmaxf(v, __shfl_xor(v, 2));
        v = fmaxf(v, __shfl_xor(v, 4));
        v = fmaxf(v, __shfl_xor(v, 8));
        rm[r] = v;
      }
      if (lm == 0) {
        const int nrow = nb + lk * 4;
#pragma unroll
        for (int r = 0; r < 4; r++)
          outmax[(size_t)((b * CN + nrow + r) * CHH + h)] = rm[r];
      }
    } else {
      bmax = fmaxf(fmaxf(bmax, fmaxf(rm[0], rm[1])), fmaxf(rm[2], rm[3]));
    }
  }
  if (!ROWMAX) {
    float v = bmax;
#pragma unroll
    for (int d = 1; d < 64; d <<= 1) v = fmaxf(v, __shfl_xor(v, d));
    __shared__ float wred[4];
    if (l == 0) wred[w] = v;
    __syncthreads();
    if (threadIdx.x == 0)
      outmax[blockIdx.x] = fmaxf(fmaxf(wred[0], wred[1]), fmaxf(wred[2], wred[3]));
  }
}

// ---- k2b: reduce 8 chunk maxes -> per-bh max
__global__ void k2b_max(const float* __restrict__ partmax, float* __restrict__ wmax) {
  const int bh = threadIdx.x;  // 128 threads
  float m = -1e30f;
#pragma unroll
  for (int c = 0; c < 8; c++) m = fmaxf(m, partmax[bh * 8 + c]);
  wmax[bh] = m;
}

// ---- kp_emit: out = ratio*(exp(dd - 0.5*diag - mx) + eps).
//      V1P=0: mx = wmax[bh] (uniform). V1P=1: mx = rowmax[row].
template <int V1P>
__global__ __launch_bounds__(256) void kp_emit(
    const float* __restrict__ inp, const float* __restrict__ proj,
    const float* __restrict__ mxin, float* __restrict__ outp) {
  const int l = threadIdx.x & 63, w = threadIdx.x >> 6;
  const int lm = l & 15, lk = l >> 4, ko = lk * 8;
  LOAD_BFRAGS(proj, lm, ko);
  const int bh = blockIdx.x >> 3, ch = blockIdx.x & 7;
  const int b = bh >> 3, h = bh & 7;
  const float whm = V1P ? 0.f : mxin[bh];
  for (int s = 0; s < 8; s++) {
    const int nb = ch * 512 + w * 128 + s * 16;
    const size_t rA = (size_t)((b * CN + nb + lm) * CHH + h);
    const float* pa = inp + rA * 64 + ko;
    float4 a0 = scl4(*(const float4*)(pa), KSCALE);
    float4 a1 = scl4(*(const float4*)(pa + 4), KSCALE);
    float4 a2 = scl4(*(const float4*)(pa + 32), KSCALE);
    float4 a3 = scl4(*(const float4*)(pa + 36), KSCALE);
    bf16x8 Ah0, Al0, Ah1, Al1;
    split8(a0, a1, Ah0, Al0);
    split8(a2, a3, Ah1, Al1);
    // exact f32 diag: partial over this lane's 16 k, reduce over k-groups
    float dp = dot4(a0, a0) + dot4(a1, a1) + dot4(a2, a2) + dot4(a3, a3);
    dp += __shfl_xor(dp, 16);
    dp += __shfl_xor(dp, 32);           // lane now has diag of row lm
    float c[4];
    size_t obase[4];
#pragma unroll
    for (int r = 0; r < 4; r++) {
      const float dg = __shfl(dp, lk * 4 + r);  // diag of row lk*4+r
      const size_t rr = (size_t)((b * CN + nb + lk * 4 + r) * CHH + h);
      const float mxr = V1P ? mxin[rr] : whm;
      c[r] = -(0.5f * dg + mxr);
      obase[r] = rr * CM + lm;
    }
#pragma unroll
    for (int t = 0; t < 8; t++) {
      f32x4 acc = {0.f, 0.f, 0.f, 0.f};
      acc = MFMA_B16(Ah0, Bh0[t], acc);
      acc = MFMA_B16(Ah1, Bh1[t], acc);
      acc = MFMA_B16(Al0, Bh0[t], acc);
      acc = MFMA_B16(Al1, Bh1[t], acc);
      acc = MFMA_B16(Ah0, Bl0[t], acc);
      acc = MFMA_B16(Ah1, Bl1[t], acc);
#pragma unroll
      for (int r = 0; r < 4; r++)
        outp[obase[r] + t * 16] = KRATIO * (__expf(acc[r] + c[r]) + KEPS);
    }
  }
}

// ---- K3: partial v2x = v2p^T @ x. LDS tiles, acc[4 j][8 d] per thread. (r4)
__global__ __launch_bounds__(256) void k3_v2x(
    const float* __restrict__ v2p, const float* __restrict__ x,
    float* __restrict__ part, float* __restrict__ vsumpart) {
  __shared__ float4 tv[1024];  // v2p tile [32 n][32 f4 = 128 j]  16KB
  __shared__ float4 tx[512];   // x   tile [32 n][16 f4 = 64 d]    8KB
  const int bh = blockIdx.x >> 3, ch = blockIdx.x & 7;
  const int b = bh >> 3, h = bh & 7;
  const int tj = threadIdx.x >> 3, td = threadIdx.x & 7;
  float acc[4][8];
  float vs[4] = {0.f, 0.f, 0.f, 0.f};
#pragma unroll
  for (int i = 0; i < 4; i++)
#pragma unroll
    for (int k = 0; k < 8; k++) acc[i][k] = 0.f;
  for (int t0 = 0; t0 < 512; t0 += 32) {
    const int nb = ch * 512 + t0;
    __syncthreads();
    for (int q = threadIdx.x; q < 1024; q += 256) {
      int nn = q >> 5, c4 = q & 31;
      tv[q] = *((const float4*)(v2p + (size_t)((b * CN + nb + nn) * CHH + h) * CM) + c4);
    }
    for (int q = threadIdx.x; q < 512; q += 256) {
      int nn = q >> 4, c4 = q & 15;
      tx[q] = *((const float4*)(x + (size_t)((b * CN + nb + nn) * CHH + h) * CD) + c4);
    }
    __syncthreads();
    for (int nn = 0; nn < 32; nn++) {
      float4 aa = tv[nn * 32 + tj];
      float4 x0 = tx[nn * 16 + td * 2], x1 = tx[nn * 16 + td * 2 + 1];
      float av[4] = {aa.x, aa.y, aa.z, aa.w};
#pragma unroll
      for (int jj = 0; jj < 4; jj++) {
        acc[jj][0] = fmaf(av[jj], x0.x, acc[jj][0]);
        acc[jj][1] = fmaf(av[jj], x0.y, acc[jj][1]);
        acc[jj][2] = fmaf(av[jj], x0.z, acc[jj][2]);
        acc[jj][3] = fmaf(av[jj], x0.w, acc[jj][3]);
        acc[jj][4] = fmaf(av[jj], x1.x, acc[jj][4]);
        acc[jj][5] = fmaf(av[jj], x1.y, acc[jj][5]);
        acc[jj][6] = fmaf(av[jj], x1.z, acc[jj][6]);
        acc[jj][7] = fmaf(av[jj], x1.w, acc[jj][7]);
      }
      vs[0] += aa.x; vs[1] += aa.y; vs[2] += aa.z; vs[3] += aa.w;
    }
  }
  const size_t pbase = (size_t)blockIdx.x * 8192;
#pragma unroll
  for (int jj = 0; jj < 4; jj++) {
    *(float4*)(part + pbase + (tj * 4 + jj) * 64 + td * 8) =
        make_float4(acc[jj][0], acc[jj][1], acc[jj][2], acc[jj][3]);
    *(float4*)(part + pbase + (tj * 4 + jj) * 64 + td * 8 + 4) =
        make_float4(acc[jj][4], acc[jj][5], acc[jj][6], acc[jj][7]);
  }
  if (td == 0) {
#pragma unroll
    for (int jj = 0; jj < 4; jj++) vsumpart[blockIdx.x * 128 + tj * 4 + jj] = vs[jj];
  }
}

// ---- K3b: reduce 8 partials -> v2x, v2sum  (grid EXACTLY 4160, guarded)
__global__ void k3b_reduce(const float* __restrict__ part, const float* __restrict__ vsumpart,
                           float* __restrict__ v2x, float* __restrict__ vsum) {
  const int i = blockIdx.x * 256 + threadIdx.x;
  if (i < 1048576) {
    const int bh = i >> 13, r = i & 8191;
    float s = 0.f;
#pragma unroll
    for (int c = 0; c < 8; c++) s += part[(size_t)(bh * 8 + c) * 8192 + r];
    v2x[i] = s;
  } else if (i < 1048576 + 16384) {
    const int k = i - 1048576, bh = k >> 7, j = k & 127;
    float s = 0.f;
#pragma unroll
    for (int c = 0; c < 8; c++) s += vsumpart[(bh * 8 + c) * 128 + j];
    vsum[k] = s;
  }
}

// ---- K4b: out0 = (v1p @ v2x) / (v1p . v2sum). (r4, verified)
__global__ __launch_bounds__(256) void k4b_out(
    const float* __restrict__ v1p, const float* __restrict__ v2xg,
    const float* __restrict__ vsumg, float* __restrict__ out0) {
  __shared__ float4 xv[2048];      // v2x [128 j][16 f4]  32KB
  __shared__ float vsh[128];
  __shared__ float tp[256 * 18];   // v1p^T tile [256 rows][16 j] pad 18
  const int bh = blockIdx.x >> 4, ch = blockIdx.x & 15;
  const int b = bh >> 3, h = bh & 7;
  for (int i = threadIdx.x; i < 2048; i += 256) xv[i] = *((const float4*)v2xg + (size_t)bh * 2048 + i);
  if (threadIdx.x < 128) vsh[threadIdx.x] = vsumg[bh * 128 + threadIdx.x];
  const int nloc = threadIdx.x;
  const int nbase = ch * 256;
  float4 acc4[16];
#pragma unroll
  for (int q = 0; q < 16; q++) acc4[q] = make_float4(0.f, 0.f, 0.f, 0.f);
  float o2 = 0.f;
  for (int jb = 0; jb < 8; jb++) {
    __syncthreads();
    for (int i = threadIdx.x; i < 2048; i += 256) {
      const int row = i >> 3, q = i & 7;
      const float2 t = *((const float2*)(v1p + (size_t)((b * CN + nbase + row) * CHH + h) * CM + jb * 16) + q);
      *(float2*)(&tp[row * 18 + q * 2]) = t;
    }
    __syncthreads();
#pragma unroll
    for (int j = 0; j < 16; j++) {
      const int jg = jb * 16 + j;
      const float p = tp[nloc * 18 + j];
      const float4* xr = &xv[jg * 16];
#pragma unroll
      for (int q = 0; q < 16; q++) fma4(acc4[q], p, xr[q]);
      o2 = fmaf(p, vsh[jg], o2);
    }
  }
  const float inv = 1.0f / o2;
  float4* ob = (float4*)(out0 + (size_t)((b * CN + nbase + nloc) * CHH + h) * CD);
#pragma unroll
  for (int q = 0; q < 16; q++) ob[q] = scl4(acc4[q], inv);
}

extern "C" void kernel_launch(void* const* d_in, const int* in_sizes, int n_in,
                              void* d_out, int out_size, void* d_ws, size_t ws_size,
                              hipStream_t stream) {
  (void)in_sizes; (void)n_in; (void)out_size; (void)ws_size;
  const float* x    = (const float*)d_in[0];
  const float* nv1  = (const float*)d_in[1];
  const float* nv2  = (const float*)d_in[2];
  const float* proj = (const float*)d_in[3];
  float* out  = (float*)d_out;
  float* out0 = out;
  float* v1p  = out + V1P_OFF;
  float* v2p  = out + V2P_OFF;

  // Scratch in the v1p output region (dead until kp_emit<1> writes v1p,
  // which runs AFTER k3/k3b consume these):
  float* part     = v1p;                  // 1024*8192 floats
  float* vsumpart = v1p + 8389632;        // 1024*128 floats
  // rowmax in the out0 region (dead until k4b writes out0):
  float* rowmax   = out0;                 // 524,288 floats (2 MB)
  // Persistent scratch in ws (~4.3 MB):
  float* ws      = (float*)d_ws;
  float* wmax    = ws;                    // 128
  float* vsum    = ws + 128;              // 16,384
  float* v2x     = ws + 16512;            // 1,048,576
  float* partmax = ws + 16512 + 1048576;  // 1,024

  kp_stat<0><<<dim3(1024), dim3(256), 0, stream>>>(nv2, proj, partmax);
  k2b_max   <<<dim3(1),    dim3(128), 0, stream>>>(partmax, wmax);
  kp_emit<0><<<dim3(1024), dim3(256), 0, stream>>>(nv2, proj, wmax, v2p);
  k3_v2x    <<<dim3(1024), dim3(256), 0, stream>>>(v2p, x, part, vsumpart);
  k3b_reduce<<<dim3(4160), dim3(256), 0, stream>>>(part, vsumpart, v2x, vsum);
  kp_stat<1><<<dim3(1024), dim3(256), 0, stream>>>(nv1, proj, rowmax);
  kp_emit<1><<<dim3(1024), dim3(256), 0, stream>>>(nv1, proj, rowmax, v1p);
  k4b_out   <<<dim3(2048), dim3(256), 0, stream>>>(v1p, v2x, vsum, out0);
}

// Round 10
// 607.082 us; speedup vs baseline: 1.7281x; 1.1198x over previous
//
#include <hip/hip_runtime.h>
#include <math.h>

constexpr int CN = 4096, CHH = 8, CD = 64, CM = 128;
constexpr int V1P_OFF = 16 * 4096 * 8 * 64;             // 33554432 floats
constexpr int V2P_OFF = V1P_OFF + 16 * 4096 * 8 * 128;  // 100663296 floats
constexpr float KSCALE = 0.35355339059327373f;          // 64^-0.25 (tau=1)
constexpr float KRATIO = 0.08838834764831843f;          // 1/sqrt(128)
constexpr float KEPS   = 1e-6f;

typedef __attribute__((ext_vector_type(8))) short bf16x8;
typedef __attribute__((ext_vector_type(4))) float f32x4;

__device__ __forceinline__ float dot4(float4 a, float4 b) {
  return fmaf(a.x, b.x, fmaf(a.y, b.y, fmaf(a.z, b.z, a.w * b.w)));
}
__device__ __forceinline__ float4 scl4(float4 a, float s) {
  return make_float4(a.x * s, a.y * s, a.z * s, a.w * s);
}
__device__ __forceinline__ short bhi(float f) {
  return (short)(__float_as_uint(f) >> 16);          // truncate to bf16
}
__device__ __forceinline__ float bf2f(short s) {
  return __uint_as_float(((unsigned)(unsigned short)s) << 16);
}
__device__ __forceinline__ void split8(float4 u, float4 v, bf16x8& hi, bf16x8& lo) {
  float a[8] = {u.x, u.y, u.z, u.w, v.x, v.y, v.z, v.w};
#pragma unroll
  for (int e = 0; e < 8; e++) {
    short h = bhi(a[e]);
    hi[e] = h;
    lo[e] = bhi(a[e] - bf2f(h));
  }
}
__device__ __forceinline__ void split8a(const float* a, bf16x8& hi, bf16x8& lo) {
#pragma unroll
  for (int e = 0; e < 8; e++) {
    short h = bhi(a[e]);
    hi[e] = h;
    lo[e] = bhi(a[e] - bf2f(h));
  }
}

#define MFMA_B16(A, B, C) __builtin_amdgcn_mfma_f32_16x16x32_bf16(A, B, C, 0, 0, 0)

// load proj into B fragments (8 col-tiles x 2 K-halves x hi/lo), ~128 VGPR
#define LOAD_BFRAGS(proj, lm, ko)                                   \
  bf16x8 Bh0[8], Bl0[8], Bh1[8], Bl1[8];                            \
  _Pragma("unroll")                                                 \
  for (int t = 0; t < 8; t++) {                                     \
    const float* pb = (proj) + (t * 16 + (lm)) * 64 + (ko);         \
    float4 p0 = *(const float4*)(pb);                               \
    float4 p1 = *(const float4*)(pb + 4);                           \
    float4 p2 = *(const float4*)(pb + 32);                          \
    float4 p3 = *(const float4*)(pb + 36);                          \
    split8(p0, p1, Bh0[t], Bl0[t]);                                 \
    split8(p2, p3, Bh1[t], Bl1[t]);                                 \
  }

// ---- kp_stat: projection max (r8, verified). ROWMAX=0: bh-chunk max;
//      ROWMAX=1: per-row max.
template <int ROWMAX>
__global__ __launch_bounds__(256) void kp_stat(
    const float* __restrict__ inp, const float* __restrict__ proj,
    float* __restrict__ outmax) {
  const int l = threadIdx.x & 63, w = threadIdx.x >> 6;
  const int lm = l & 15, lk = l >> 4, ko = lk * 8;
  LOAD_BFRAGS(proj, lm, ko);
  const int bh = blockIdx.x >> 3, ch = blockIdx.x & 7;
  const int b = bh >> 3, h = bh & 7;
  float bmax = -1e30f;
  for (int s = 0; s < 8; s++) {
    const int nb = ch * 512 + w * 128 + s * 16;
    const size_t rA = (size_t)((b * CN + nb + lm) * CHH + h);
    const float* pa = inp + rA * 64 + ko;
    float4 a0 = scl4(*(const float4*)(pa), KSCALE);
    float4 a1 = scl4(*(const float4*)(pa + 4), KSCALE);
    float4 a2 = scl4(*(const float4*)(pa + 32), KSCALE);
    float4 a3 = scl4(*(const float4*)(pa + 36), KSCALE);
    bf16x8 Ah0, Al0, Ah1, Al1;
    split8(a0, a1, Ah0, Al0);
    split8(a2, a3, Ah1, Al1);
    float rm[4] = {-1e30f, -1e30f, -1e30f, -1e30f};
#pragma unroll
    for (int t = 0; t < 8; t++) {
      f32x4 acc = {0.f, 0.f, 0.f, 0.f};
      acc = MFMA_B16(Ah0, Bh0[t], acc);
      acc = MFMA_B16(Ah1, Bh1[t], acc);
      acc = MFMA_B16(Al0, Bh0[t], acc);
      acc = MFMA_B16(Al1, Bh1[t], acc);
      acc = MFMA_B16(Ah0, Bl0[t], acc);
      acc = MFMA_B16(Ah1, Bl1[t], acc);
#pragma unroll
      for (int r = 0; r < 4; r++) rm[r] = fmaxf(rm[r], acc[r]);
    }
    if (ROWMAX) {
#pragma unroll
      for (int r = 0; r < 4; r++) {
        float v = rm[r];
        v = fmaxf(v, __shfl_xor(v, 1));
        v = fmaxf(v, __shfl_xor(v, 2));
        v = fmaxf(v, __shfl_xor(v, 4));
        v = fmaxf(v, __shfl_xor(v, 8));
        rm[r] = v;
      }
      if (lm == 0) {
        const int nrow = nb + lk * 4;
#pragma unroll
        for (int r = 0; r < 4; r++)
          outmax[(size_t)((b * CN + nrow + r) * CHH + h)] = rm[r];
      }
    } else {
      bmax = fmaxf(fmaxf(bmax, fmaxf(rm[0], rm[1])), fmaxf(rm[2], rm[3]));
    }
  }
  if (!ROWMAX) {
    float v = bmax;
#pragma unroll
    for (int d = 1; d < 64; d <<= 1) v = fmaxf(v, __shfl_xor(v, d));
    __shared__ float wred[4];
    if (l == 0) wred[w] = v;
    __syncthreads();
    if (threadIdx.x == 0)
      outmax[blockIdx.x] = fmaxf(fmaxf(wred[0], wred[1]), fmaxf(wred[2], wred[3]));
  }
}

// ---- k2b: reduce 8 chunk maxes -> per-bh max
__global__ void k2b_max(const float* __restrict__ partmax, float* __restrict__ wmax) {
  const int bh = threadIdx.x;  // 128 threads
  float m = -1e30f;
#pragma unroll
  for (int c = 0; c < 8; c++) m = fmaxf(m, partmax[bh * 8 + c]);
  wmax[bh] = m;
}

// ---- kp_emit: out = ratio*(exp(dd - 0.5*diag - mx) + eps) (r8, verified)
template <int V1P>
__global__ __launch_bounds__(256) void kp_emit(
    const float* __restrict__ inp, const float* __restrict__ proj,
    const float* __restrict__ mxin, float* __restrict__ outp) {
  const int l = threadIdx.x & 63, w = threadIdx.x >> 6;
  const int lm = l & 15, lk = l >> 4, ko = lk * 8;
  LOAD_BFRAGS(proj, lm, ko);
  const int bh = blockIdx.x >> 3, ch = blockIdx.x & 7;
  const int b = bh >> 3, h = bh & 7;
  const float whm = V1P ? 0.f : mxin[bh];
  for (int s = 0; s < 8; s++) {
    const int nb = ch * 512 + w * 128 + s * 16;
    const size_t rA = (size_t)((b * CN + nb + lm) * CHH + h);
    const float* pa = inp + rA * 64 + ko;
    float4 a0 = scl4(*(const float4*)(pa), KSCALE);
    float4 a1 = scl4(*(const float4*)(pa + 4), KSCALE);
    float4 a2 = scl4(*(const float4*)(pa + 32), KSCALE);
    float4 a3 = scl4(*(const float4*)(pa + 36), KSCALE);
    bf16x8 Ah0, Al0, Ah1, Al1;
    split8(a0, a1, Ah0, Al0);
    split8(a2, a3, Ah1, Al1);
    float dp = dot4(a0, a0) + dot4(a1, a1) + dot4(a2, a2) + dot4(a3, a3);
    dp += __shfl_xor(dp, 16);
    dp += __shfl_xor(dp, 32);
    float c[4];
    size_t obase[4];
#pragma unroll
    for (int r = 0; r < 4; r++) {
      const float dg = __shfl(dp, lk * 4 + r);
      const size_t rr = (size_t)((b * CN + nb + lk * 4 + r) * CHH + h);
      const float mxr = V1P ? mxin[rr] : whm;
      c[r] = -(0.5f * dg + mxr);
      obase[r] = rr * CM + lm;
    }
#pragma unroll
    for (int t = 0; t < 8; t++) {
      f32x4 acc = {0.f, 0.f, 0.f, 0.f};
      acc = MFMA_B16(Ah0, Bh0[t], acc);
      acc = MFMA_B16(Ah1, Bh1[t], acc);
      acc = MFMA_B16(Al0, Bh0[t], acc);
      acc = MFMA_B16(Al1, Bh1[t], acc);
      acc = MFMA_B16(Ah0, Bl0[t], acc);
      acc = MFMA_B16(Ah1, Bl1[t], acc);
#pragma unroll
      for (int r = 0; r < 4; r++)
        outp[obase[r] + t * 16] = KRATIO * (__expf(acc[r] + c[r]) + KEPS);
    }
  }
}

// ---- k3m: partial v2x = v2p^T @ x via MFMA. m=j, n=d, k=n-rows.
//      GRID = 4096 (128 bh x 32 ch). r9 bug: launched 512 -> bh>=16 got
//      zero partials -> vsum=0 -> 0*inf=NaN in k4m.
__global__ __launch_bounds__(256) void k3m(
    const float* __restrict__ v2p, const float* __restrict__ x,
    float* __restrict__ part, float* __restrict__ vsumpart) {
  const int l = threadIdx.x & 63, w = threadIdx.x >> 6;
  const int lm = l & 15, lk = l >> 4;
  const int bh = blockIdx.x >> 5, ch = blockIdx.x & 31;
  const int b = bh >> 3, h = bh & 7;
  const int jt0 = w * 2;
  f32x4 acc[2][4];
#pragma unroll
  for (int jj = 0; jj < 2; jj++)
#pragma unroll
    for (int dt = 0; dt < 4; dt++) acc[jj][dt] = (f32x4){0.f, 0.f, 0.f, 0.f};
  float vs0 = 0.f, vs1 = 0.f;
  for (int t = 0; t < 4; t++) {
    const int n0 = ch * 128 + t * 32 + lk * 8;       // this lane's k-row base
    bf16x8 Ah[2], Al[2];
#pragma unroll
    for (int jj = 0; jj < 2; jj++) {
      float af[8];
#pragma unroll
      for (int e = 0; e < 8; e++)
        af[e] = v2p[(size_t)((b * CN + n0 + e) * CHH + h) * CM + (jt0 + jj) * 16 + lm];
      split8a(af, Ah[jj], Al[jj]);
      float p = 0.f;
#pragma unroll
      for (int e = 0; e < 8; e++) p += af[e];
      if (jj == 0) vs0 += p; else vs1 += p;
    }
#pragma unroll
    for (int dt = 0; dt < 4; dt++) {
      float bfv[8];
#pragma unroll
      for (int e = 0; e < 8; e++)
        bfv[e] = x[(size_t)((b * CN + n0 + e) * CHH + h) * CD + dt * 16 + lm];
      bf16x8 Bh, Bl;
      split8a(bfv, Bh, Bl);
#pragma unroll
      for (int jj = 0; jj < 2; jj++) {
        acc[jj][dt] = MFMA_B16(Ah[jj], Bh, acc[jj][dt]);
        acc[jj][dt] = MFMA_B16(Al[jj], Bh, acc[jj][dt]);
        acc[jj][dt] = MFMA_B16(Ah[jj], Bl, acc[jj][dt]);
      }
    }
  }
  const size_t pbase = (size_t)blockIdx.x * 8192;     // = (bh*32+ch)*8192
#pragma unroll
  for (int jj = 0; jj < 2; jj++)
#pragma unroll
    for (int dt = 0; dt < 4; dt++)
#pragma unroll
      for (int r = 0; r < 4; r++)
        part[pbase + ((size_t)(jt0 + jj) * 16 + lk * 4 + r) * 64 + dt * 16 + lm] = acc[jj][dt][r];
  float v0 = vs0, v1 = vs1;
  v0 += __shfl_xor(v0, 16); v0 += __shfl_xor(v0, 32);
  v1 += __shfl_xor(v1, 16); v1 += __shfl_xor(v1, 32);
  if (lk == 0) {
    vsumpart[(size_t)blockIdx.x * 128 + (jt0 + 0) * 16 + lm] = v0;
    vsumpart[(size_t)blockIdx.x * 128 + (jt0 + 1) * 16 + lm] = v1;
  }
}

// ---- k3b: reduce 32 partials -> v2x, v2sum  (grid EXACTLY 4160, guarded)
__global__ void k3b_reduce(const float* __restrict__ part, const float* __restrict__ vsumpart,
                           float* __restrict__ v2x, float* __restrict__ vsum) {
  const int i = blockIdx.x * 256 + threadIdx.x;
  if (i < 1048576) {
    const int bh = i >> 13, r = i & 8191;
    float s = 0.f;
#pragma unroll
    for (int c = 0; c < 32; c++) s += part[(size_t)(bh * 32 + c) * 8192 + r];
    v2x[i] = s;
  } else if (i < 1048576 + 16384) {
    const int k = i - 1048576, bh = k >> 7, j = k & 127;
    float s = 0.f;
#pragma unroll
    for (int c = 0; c < 32; c++) s += vsumpart[(size_t)(bh * 32 + c) * 128 + j];
    vsum[k] = s;
  }
}

// ---- k4m: out0 = (v1p @ v2x) / (v1p . vsum) via MFMA. m=n-rows, k=j.
__global__ __launch_bounds__(256) void k4m(
    const float* __restrict__ v1p, const float* __restrict__ v2xg,
    const float* __restrict__ vsumg, float* __restrict__ out0) {
  const int l = threadIdx.x & 63, dt = threadIdx.x >> 6;  // wave = d-tile
  const int lm = l & 15, lk = l >> 4;
  const int bh = blockIdx.x >> 4, ch = blockIdx.x & 15;
  const int b = bh >> 3, h = bh & 7;
  bf16x8 Bh[4], Bl[4];
#pragma unroll
  for (int kc = 0; kc < 4; kc++) {
    float bfv[8];
#pragma unroll
    for (int e = 0; e < 8; e++)
      bfv[e] = v2xg[(size_t)bh * 8192 + (size_t)(kc * 32 + lk * 8 + e) * 64 + dt * 16 + lm];
    split8a(bfv, Bh[kc], Bl[kc]);
  }
  float vsr[4][8];
#pragma unroll
  for (int kc = 0; kc < 4; kc++)
#pragma unroll
    for (int e = 0; e < 8; e++)
      vsr[kc][e] = vsumg[bh * 128 + kc * 32 + lk * 8 + e];
  for (int s = 0; s < 16; s++) {
    const int nb = ch * 256 + s * 16;
    const float* pa = v1p + (size_t)((b * CN + nb + lm) * CHH + h) * CM;
    bf16x8 Ah[4], Al[4];
    float o2p = 0.f;
#pragma unroll
    for (int kc = 0; kc < 4; kc++) {
      float4 u = *(const float4*)(pa + kc * 32 + lk * 8);
      float4 v = *(const float4*)(pa + kc * 32 + lk * 8 + 4);
      split8(u, v, Ah[kc], Al[kc]);
      o2p += u.x * vsr[kc][0] + u.y * vsr[kc][1] + u.z * vsr[kc][2] + u.w * vsr[kc][3]
           + v.x * vsr[kc][4] + v.y * vsr[kc][5] + v.z * vsr[kc][6] + v.w * vsr[kc][7];
    }
    o2p += __shfl_xor(o2p, 16);
    o2p += __shfl_xor(o2p, 32);          // lane l: o2 of row (l&15)
    f32x4 acc = {0.f, 0.f, 0.f, 0.f};
#pragma unroll
    for (int kc = 0; kc < 4; kc++) {
      acc = MFMA_B16(Ah[kc], Bh[kc], acc);
      acc = MFMA_B16(Al[kc], Bh[kc], acc);
      acc = MFMA_B16(Ah[kc], Bl[kc], acc);
    }
#pragma unroll
    for (int r = 0; r < 4; r++) {
      const float inv = 1.0f / __shfl(o2p, lk * 4 + r);
      out0[(size_t)((b * CN + nb + lk * 4 + r) * CHH + h) * CD + dt * 16 + lm] = acc[r] * inv;
    }
  }
}

extern "C" void kernel_launch(void* const* d_in, const int* in_sizes, int n_in,
                              void* d_out, int out_size, void* d_ws, size_t ws_size,
                              hipStream_t stream) {
  (void)in_sizes; (void)n_in; (void)out_size; (void)ws_size;
  const float* x    = (const float*)d_in[0];
  const float* nv1  = (const float*)d_in[1];
  const float* nv2  = (const float*)d_in[2];
  const float* proj = (const float*)d_in[3];
  float* out  = (float*)d_out;
  float* out0 = out;
  float* v1p  = out + V1P_OFF;
  float* v2p  = out + V2P_OFF;

  // Scratch in the v1p output region (67,108,864 floats; consumed by k3b
  // BEFORE kp_emit<1> writes v1p):
  float* part     = v1p;                  // 4096*8192 = 33,554,432 floats
  float* vsumpart = v1p + 33554432;       // 4096*128 = 524,288 floats
  // rowmax in the out0 region (dead until k4m writes out0):
  float* rowmax   = out0;                 // 524,288 floats (2 MB)
  // Persistent scratch in ws (~4.3 MB):
  float* ws      = (float*)d_ws;
  float* wmax    = ws;                    // 128
  float* vsum    = ws + 128;              // 16,384
  float* v2x     = ws + 16512;            // 1,048,576
  float* partmax = ws + 16512 + 1048576;  // 1,024

  kp_stat<0><<<dim3(1024), dim3(256), 0, stream>>>(nv2, proj, partmax);
  k2b_max   <<<dim3(1),    dim3(128), 0, stream>>>(partmax, wmax);
  kp_emit<0><<<dim3(1024), dim3(256), 0, stream>>>(nv2, proj, wmax, v2p);
  k3m       <<<dim3(4096), dim3(256), 0, stream>>>(v2p, x, part, vsumpart);
  k3b_reduce<<<dim3(4160), dim3(256), 0, stream>>>(part, vsumpart, v2x, vsum);
  kp_stat<1><<<dim3(1024), dim3(256), 0, stream>>>(nv1, proj, rowmax);
  kp_emit<1><<<dim3(1024), dim3(256), 0, stream>>>(nv1, proj, rowmax, v1p);
  k4m       <<<dim3(2048), dim3(256), 0, stream>>>(v1p, v2x, vsum, out0);
}

// Round 11
// 507.927 us; speedup vs baseline: 2.0654x; 1.1952x over previous
//
#include <hip/hip_runtime.h>
#include <math.h>

constexpr int CN = 4096, CHH = 8, CD = 64, CM = 128;
constexpr int V1P_OFF = 16 * 4096 * 8 * 64;             // 33554432 floats
constexpr int V2P_OFF = V1P_OFF + 16 * 4096 * 8 * 128;  // 100663296 floats
constexpr float KSCALE = 0.35355339059327373f;          // 64^-0.25 (tau=1)
constexpr float KRATIO = 0.08838834764831843f;          // 1/sqrt(128)
constexpr float KEPS   = 1e-6f;

typedef __attribute__((ext_vector_type(8))) short bf16x8;
typedef __attribute__((ext_vector_type(4))) float f32x4;

__device__ __forceinline__ float dot4(float4 a, float4 b) {
  return fmaf(a.x, b.x, fmaf(a.y, b.y, fmaf(a.z, b.z, a.w * b.w)));
}
__device__ __forceinline__ float4 scl4(float4 a, float s) {
  return make_float4(a.x * s, a.y * s, a.z * s, a.w * s);
}
__device__ __forceinline__ short bhi(float f) {
  return (short)(__float_as_uint(f) >> 16);          // truncate to bf16
}
__device__ __forceinline__ float bf2f(short s) {
  return __uint_as_float(((unsigned)(unsigned short)s) << 16);
}
__device__ __forceinline__ void split8(float4 u, float4 v, bf16x8& hi, bf16x8& lo) {
  float a[8] = {u.x, u.y, u.z, u.w, v.x, v.y, v.z, v.w};
#pragma unroll
  for (int e = 0; e < 8; e++) {
    short h = bhi(a[e]);
    hi[e] = h;
    lo[e] = bhi(a[e] - bf2f(h));
  }
}
__device__ __forceinline__ void split8a(const float* a, bf16x8& hi, bf16x8& lo) {
#pragma unroll
  for (int e = 0; e < 8; e++) {
    short h = bhi(a[e]);
    hi[e] = h;
    lo[e] = bhi(a[e] - bf2f(h));
  }
}

#define MFMA_B16(A, B, C) __builtin_amdgcn_mfma_f32_16x16x32_bf16(A, B, C, 0, 0, 0)

// load proj into B fragments (8 col-tiles x 2 K-halves x hi/lo), ~128 VGPR
#define LOAD_BFRAGS(proj, lm, ko)                                   \
  bf16x8 Bh0[8], Bl0[8], Bh1[8], Bl1[8];                            \
  _Pragma("unroll")                                                 \
  for (int t = 0; t < 8; t++) {                                     \
    const float* pb = (proj) + (t * 16 + (lm)) * 64 + (ko);         \
    float4 p0 = *(const float4*)(pb);                               \
    float4 p1 = *(const float4*)(pb + 4);                           \
    float4 p2 = *(const float4*)(pb + 32);                          \
    float4 p3 = *(const float4*)(pb + 36);                          \
    split8(p0, p1, Bh0[t], Bl0[t]);                                 \
    split8(p2, p3, Bh1[t], Bl1[t]);                                 \
  }

// 6-term hi/lo MFMA chain for one j-tile t
#define PROJ_MFMA(acc, t)                                           \
  do {                                                              \
    acc = MFMA_B16(Ah0, Bh0[t], acc);                               \
    acc = MFMA_B16(Ah1, Bh1[t], acc);                               \
    acc = MFMA_B16(Al0, Bh0[t], acc);                               \
    acc = MFMA_B16(Al1, Bh1[t], acc);                               \
    acc = MFMA_B16(Ah0, Bl0[t], acc);                               \
    acc = MFMA_B16(Ah1, Bl1[t], acc);                               \
  } while (0)

// ---- kp_stat: per-(b,h)-chunk max of dd for v2 (r8, verified)
__global__ __launch_bounds__(256) void kp_stat(
    const float* __restrict__ inp, const float* __restrict__ proj,
    float* __restrict__ outmax) {
  const int l = threadIdx.x & 63, w = threadIdx.x >> 6;
  const int lm = l & 15, lk = l >> 4, ko = lk * 8;
  LOAD_BFRAGS(proj, lm, ko);
  const int bh = blockIdx.x >> 3, ch = blockIdx.x & 7;
  const int b = bh >> 3, h = bh & 7;
  float bmax = -1e30f;
  for (int s = 0; s < 8; s++) {
    const int nb = ch * 512 + w * 128 + s * 16;
    const size_t rA = (size_t)((b * CN + nb + lm) * CHH + h);
    const float* pa = inp + rA * 64 + ko;
    float4 a0 = scl4(*(const float4*)(pa), KSCALE);
    float4 a1 = scl4(*(const float4*)(pa + 4), KSCALE);
    float4 a2 = scl4(*(const float4*)(pa + 32), KSCALE);
    float4 a3 = scl4(*(const float4*)(pa + 36), KSCALE);
    bf16x8 Ah0, Al0, Ah1, Al1;
    split8(a0, a1, Ah0, Al0);
    split8(a2, a3, Ah1, Al1);
    float rm[4] = {-1e30f, -1e30f, -1e30f, -1e30f};
#pragma unroll
    for (int t = 0; t < 8; t++) {
      f32x4 acc = {0.f, 0.f, 0.f, 0.f};
      PROJ_MFMA(acc, t);
#pragma unroll
      for (int r = 0; r < 4; r++) rm[r] = fmaxf(rm[r], acc[r]);
    }
    bmax = fmaxf(fmaxf(bmax, fmaxf(rm[0], rm[1])), fmaxf(rm[2], rm[3]));
  }
  float v = bmax;
#pragma unroll
  for (int d = 1; d < 64; d <<= 1) v = fmaxf(v, __shfl_xor(v, d));
  __shared__ float wred[4];
  if (l == 0) wred[w] = v;
  __syncthreads();
  if (threadIdx.x == 0)
    outmax[blockIdx.x] = fmaxf(fmaxf(wred[0], wred[1]), fmaxf(wred[2], wred[3]));
}

// ---- k2b: reduce 8 chunk maxes -> per-bh max
__global__ void k2b_max(const float* __restrict__ partmax, float* __restrict__ wmax) {
  const int bh = threadIdx.x;  // 128 threads
  float m = -1e30f;
#pragma unroll
  for (int c = 0; c < 8; c++) m = fmaxf(m, partmax[bh * 8 + c]);
  wmax[bh] = m;
}

// ---- kp_emit: v2p = ratio*(exp(dd - 0.5*diag - wmax[bh]) + eps) (r8)
__global__ __launch_bounds__(256) void kp_emit(
    const float* __restrict__ inp, const float* __restrict__ proj,
    const float* __restrict__ mxin, float* __restrict__ outp) {
  const int l = threadIdx.x & 63, w = threadIdx.x >> 6;
  const int lm = l & 15, lk = l >> 4, ko = lk * 8;
  LOAD_BFRAGS(proj, lm, ko);
  const int bh = blockIdx.x >> 3, ch = blockIdx.x & 7;
  const int b = bh >> 3, h = bh & 7;
  const float whm = mxin[bh];
  for (int s = 0; s < 8; s++) {
    const int nb = ch * 512 + w * 128 + s * 16;
    const size_t rA = (size_t)((b * CN + nb + lm) * CHH + h);
    const float* pa = inp + rA * 64 + ko;
    float4 a0 = scl4(*(const float4*)(pa), KSCALE);
    float4 a1 = scl4(*(const float4*)(pa + 4), KSCALE);
    float4 a2 = scl4(*(const float4*)(pa + 32), KSCALE);
    float4 a3 = scl4(*(const float4*)(pa + 36), KSCALE);
    bf16x8 Ah0, Al0, Ah1, Al1;
    split8(a0, a1, Ah0, Al0);
    split8(a2, a3, Ah1, Al1);
    float dp = dot4(a0, a0) + dot4(a1, a1) + dot4(a2, a2) + dot4(a3, a3);
    dp += __shfl_xor(dp, 16);
    dp += __shfl_xor(dp, 32);
    float c[4];
    size_t obase[4];
#pragma unroll
    for (int r = 0; r < 4; r++) {
      const float dg = __shfl(dp, lk * 4 + r);
      const size_t rr = (size_t)((b * CN + nb + lk * 4 + r) * CHH + h);
      c[r] = -(0.5f * dg + whm);
      obase[r] = rr * CM + lm;
    }
#pragma unroll
    for (int t = 0; t < 8; t++) {
      f32x4 acc = {0.f, 0.f, 0.f, 0.f};
      PROJ_MFMA(acc, t);
#pragma unroll
      for (int r = 0; r < 4; r++)
        outp[obase[r] + t * 16] = KRATIO * (__expf(acc[r] + c[r]) + KEPS);
    }
  }
}

// ---- kv1e: FUSED v1p pass. dd tile (16 rows x 128 cols) kept in acc8[8]
//      (32 statically-indexed VGPRs); per-row max = max over t + shfl_xor
//      over lm lanes; then exp + write. Saves the kp_stat<1> full pass.
__global__ __launch_bounds__(256) void kv1e(
    const float* __restrict__ inp, const float* __restrict__ proj,
    float* __restrict__ outp) {
  const int l = threadIdx.x & 63, w = threadIdx.x >> 6;
  const int lm = l & 15, lk = l >> 4, ko = lk * 8;
  LOAD_BFRAGS(proj, lm, ko);
  const int bh = blockIdx.x >> 3, ch = blockIdx.x & 7;
  const int b = bh >> 3, h = bh & 7;
  for (int s = 0; s < 8; s++) {
    const int nb = ch * 512 + w * 128 + s * 16;
    const size_t rA = (size_t)((b * CN + nb + lm) * CHH + h);
    const float* pa = inp + rA * 64 + ko;
    float4 a0 = scl4(*(const float4*)(pa), KSCALE);
    float4 a1 = scl4(*(const float4*)(pa + 4), KSCALE);
    float4 a2 = scl4(*(const float4*)(pa + 32), KSCALE);
    float4 a3 = scl4(*(const float4*)(pa + 36), KSCALE);
    bf16x8 Ah0, Al0, Ah1, Al1;
    split8(a0, a1, Ah0, Al0);
    split8(a2, a3, Ah1, Al1);
    float dp = dot4(a0, a0) + dot4(a1, a1) + dot4(a2, a2) + dot4(a3, a3);
    dp += __shfl_xor(dp, 16);
    dp += __shfl_xor(dp, 32);
    f32x4 acc8[8];
#pragma unroll
    for (int t = 0; t < 8; t++) {
      f32x4 acc = {0.f, 0.f, 0.f, 0.f};
      PROJ_MFMA(acc, t);
      acc8[t] = acc;
    }
    // per-row max over the full 128 features
    float rm[4];
#pragma unroll
    for (int r = 0; r < 4; r++) {
      float m = acc8[0][r];
#pragma unroll
      for (int t = 1; t < 8; t++) m = fmaxf(m, acc8[t][r]);
      m = fmaxf(m, __shfl_xor(m, 1));
      m = fmaxf(m, __shfl_xor(m, 2));
      m = fmaxf(m, __shfl_xor(m, 4));
      m = fmaxf(m, __shfl_xor(m, 8));
      rm[r] = m;
    }
    float c[4];
    size_t obase[4];
#pragma unroll
    for (int r = 0; r < 4; r++) {
      const float dg = __shfl(dp, lk * 4 + r);
      const size_t rr = (size_t)((b * CN + nb + lk * 4 + r) * CHH + h);
      c[r] = -(0.5f * dg + rm[r]);
      obase[r] = rr * CM + lm;
    }
#pragma unroll
    for (int t = 0; t < 8; t++) {
#pragma unroll
      for (int r = 0; r < 4; r++)
        outp[obase[r] + t * 16] = KRATIO * (__expf(acc8[t][r] + c[r]) + KEPS);
    }
  }
}

// ---- k3m: partial v2x = v2p^T @ x via MFMA. 8 chunks/bh (16 k-tiles each;
//      r10 used 32 chunks -> 134MB partials; now 33.5MB).
__global__ __launch_bounds__(256) void k3m(
    const float* __restrict__ v2p, const float* __restrict__ x,
    float* __restrict__ part, float* __restrict__ vsumpart) {
  const int l = threadIdx.x & 63, w = threadIdx.x >> 6;
  const int lm = l & 15, lk = l >> 4;
  const int bh = blockIdx.x >> 3, ch = blockIdx.x & 7;
  const int b = bh >> 3, h = bh & 7;
  const int jt0 = w * 2;
  f32x4 acc[2][4];
#pragma unroll
  for (int jj = 0; jj < 2; jj++)
#pragma unroll
    for (int dt = 0; dt < 4; dt++) acc[jj][dt] = (f32x4){0.f, 0.f, 0.f, 0.f};
  float vs0 = 0.f, vs1 = 0.f;
  for (int t = 0; t < 16; t++) {
    const int n0 = ch * 512 + t * 32 + lk * 8;       // this lane's k-row base
    bf16x8 Ah[2], Al[2];
#pragma unroll
    for (int jj = 0; jj < 2; jj++) {
      float af[8];
#pragma unroll
      for (int e = 0; e < 8; e++)
        af[e] = v2p[(size_t)((b * CN + n0 + e) * CHH + h) * CM + (jt0 + jj) * 16 + lm];
      split8a(af, Ah[jj], Al[jj]);
      float p = 0.f;
#pragma unroll
      for (int e = 0; e < 8; e++) p += af[e];
      if (jj == 0) vs0 += p; else vs1 += p;
    }
#pragma unroll
    for (int dt = 0; dt < 4; dt++) {
      float bfv[8];
#pragma unroll
      for (int e = 0; e < 8; e++)
        bfv[e] = x[(size_t)((b * CN + n0 + e) * CHH + h) * CD + dt * 16 + lm];
      bf16x8 Bh, Bl;
      split8a(bfv, Bh, Bl);
#pragma unroll
      for (int jj = 0; jj < 2; jj++) {
        acc[jj][dt] = MFMA_B16(Ah[jj], Bh, acc[jj][dt]);
        acc[jj][dt] = MFMA_B16(Al[jj], Bh, acc[jj][dt]);
        acc[jj][dt] = MFMA_B16(Ah[jj], Bl, acc[jj][dt]);
      }
    }
  }
  const size_t pbase = (size_t)blockIdx.x * 8192;     // = (bh*8+ch)*8192
#pragma unroll
  for (int jj = 0; jj < 2; jj++)
#pragma unroll
    for (int dt = 0; dt < 4; dt++)
#pragma unroll
      for (int r = 0; r < 4; r++)
        part[pbase + ((size_t)(jt0 + jj) * 16 + lk * 4 + r) * 64 + dt * 16 + lm] = acc[jj][dt][r];
  float v0 = vs0, v1 = vs1;
  v0 += __shfl_xor(v0, 16); v0 += __shfl_xor(v0, 32);
  v1 += __shfl_xor(v1, 16); v1 += __shfl_xor(v1, 32);
  if (lk == 0) {
    vsumpart[(size_t)blockIdx.x * 128 + (jt0 + 0) * 16 + lm] = v0;
    vsumpart[(size_t)blockIdx.x * 128 + (jt0 + 1) * 16 + lm] = v1;
  }
}

// ---- k3b: reduce 8 partials -> v2x, v2sum  (grid EXACTLY 4160, guarded)
__global__ void k3b_reduce(const float* __restrict__ part, const float* __restrict__ vsumpart,
                           float* __restrict__ v2x, float* __restrict__ vsum) {
  const int i = blockIdx.x * 256 + threadIdx.x;
  if (i < 1048576) {
    const int bh = i >> 13, r = i & 8191;
    float s = 0.f;
#pragma unroll
    for (int c = 0; c < 8; c++) s += part[(size_t)(bh * 8 + c) * 8192 + r];
    v2x[i] = s;
  } else if (i < 1048576 + 16384) {
    const int k = i - 1048576, bh = k >> 7, j = k & 127;
    float s = 0.f;
#pragma unroll
    for (int c = 0; c < 8; c++) s += vsumpart[(size_t)(bh * 8 + c) * 128 + j];
    vsum[k] = s;
  }
}

// ---- k4m: out0 = (v1p @ v2x) / (v1p . vsum) via MFMA (r10, verified)
__global__ __launch_bounds__(256) void k4m(
    const float* __restrict__ v1p, const float* __restrict__ v2xg,
    const float* __restrict__ vsumg, float* __restrict__ out0) {
  const int l = threadIdx.x & 63, dt = threadIdx.x >> 6;  // wave = d-tile
  const int lm = l & 15, lk = l >> 4;
  const int bh = blockIdx.x >> 4, ch = blockIdx.x & 15;
  const int b = bh >> 3, h = bh & 7;
  bf16x8 Bh[4], Bl[4];
#pragma unroll
  for (int kc = 0; kc < 4; kc++) {
    float bfv[8];
#pragma unroll
    for (int e = 0; e < 8; e++)
      bfv[e] = v2xg[(size_t)bh * 8192 + (size_t)(kc * 32 + lk * 8 + e) * 64 + dt * 16 + lm];
    split8a(bfv, Bh[kc], Bl[kc]);
  }
  float vsr[4][8];
#pragma unroll
  for (int kc = 0; kc < 4; kc++)
#pragma unroll
    for (int e = 0; e < 8; e++)
      vsr[kc][e] = vsumg[bh * 128 + kc * 32 + lk * 8 + e];
  for (int s = 0; s < 16; s++) {
    const int nb = ch * 256 + s * 16;
    const float* pa = v1p + (size_t)((b * CN + nb + lm) * CHH + h) * CM;
    bf16x8 Ah[4], Al[4];
    float o2p = 0.f;
#pragma unroll
    for (int kc = 0; kc < 4; kc++) {
      float4 u = *(const float4*)(pa + kc * 32 + lk * 8);
      float4 v = *(const float4*)(pa + kc * 32 + lk * 8 + 4);
      split8(u, v, Ah[kc], Al[kc]);
      o2p += u.x * vsr[kc][0] + u.y * vsr[kc][1] + u.z * vsr[kc][2] + u.w * vsr[kc][3]
           + v.x * vsr[kc][4] + v.y * vsr[kc][5] + v.z * vsr[kc][6] + v.w * vsr[kc][7];
    }
    o2p += __shfl_xor(o2p, 16);
    o2p += __shfl_xor(o2p, 32);          // lane l: o2 of row (l&15)
    f32x4 acc = {0.f, 0.f, 0.f, 0.f};
#pragma unroll
    for (int kc = 0; kc < 4; kc++) {
      acc = MFMA_B16(Ah[kc], Bh[kc], acc);
      acc = MFMA_B16(Al[kc], Bh[kc], acc);
      acc = MFMA_B16(Ah[kc], Bl[kc], acc);
    }
#pragma unroll
    for (int r = 0; r < 4; r++) {
      const float inv = 1.0f / __shfl(o2p, lk * 4 + r);
      out0[(size_t)((b * CN + nb + lk * 4 + r) * CHH + h) * CD + dt * 16 + lm] = acc[r] * inv;
    }
  }
}

extern "C" void kernel_launch(void* const* d_in, const int* in_sizes, int n_in,
                              void* d_out, int out_size, void* d_ws, size_t ws_size,
                              hipStream_t stream) {
  (void)in_sizes; (void)n_in; (void)out_size; (void)ws_size;
  const float* x    = (const float*)d_in[0];
  const float* nv1  = (const float*)d_in[1];
  const float* nv2  = (const float*)d_in[2];
  const float* proj = (const float*)d_in[3];
  float* out  = (float*)d_out;
  float* out0 = out;
  float* v1p  = out + V1P_OFF;
  float* v2p  = out + V2P_OFF;

  // Scratch in the v1p output region (consumed by k3b BEFORE kv1e writes v1p):
  float* part     = v1p;                  // 1024*8192 = 8,388,608 floats
  float* vsumpart = v1p + 8388608;        // 1024*128 = 131,072 floats
  // Persistent scratch in ws (~4.3 MB):
  float* ws      = (float*)d_ws;
  float* wmax    = ws;                    // 128
  float* vsum    = ws + 128;              // 16,384
  float* v2x     = ws + 16512;            // 1,048,576
  float* partmax = ws + 16512 + 1048576;  // 1,024

  kp_stat   <<<dim3(1024), dim3(256), 0, stream>>>(nv2, proj, partmax);
  k2b_max   <<<dim3(1),    dim3(128), 0, stream>>>(partmax, wmax);
  kp_emit   <<<dim3(1024), dim3(256), 0, stream>>>(nv2, proj, wmax, v2p);
  k3m       <<<dim3(1024), dim3(256), 0, stream>>>(v2p, x, part, vsumpart);
  k3b_reduce<<<dim3(4160), dim3(256), 0, stream>>>(part, vsumpart, v2x, vsum);
  kv1e      <<<dim3(1024), dim3(256), 0, stream>>>(nv1, proj, v1p);
  k4m       <<<dim3(2048), dim3(256), 0, stream>>>(v1p, v2x, vsum, out0);
}